// Round 3
// baseline (374.691 us; speedup 1.0000x reference)
//
#include <hip/hip_runtime.h>

#define N_   64
#define C_   2048
#define HW_  288
#define P_   5
#define CM_  3328   // C_ + P_*256
#define LOC_ 1280   // P_*256
#define SEGC 8      // K segments for loc GEMM  (2048/256)
#define SEGM 13     // K segments for merge GEMM (3328/256)

// ---------- DPP wave64 reductions (result valid in lane 63) ----------
template<int CTRL, int RMASK>
__device__ __forceinline__ float dpp_term(float x) {
  return __int_as_float(__builtin_amdgcn_update_dpp(0, __float_as_int(x), CTRL, RMASK, 0xF, true));
}
__device__ __forceinline__ float wave_sum63(float x) {
  x += dpp_term<0xB1, 0xF>(x);   // quad_perm xor1
  x += dpp_term<0x4E, 0xF>(x);   // quad_perm xor2
  x += dpp_term<0x141,0xF>(x);   // row_half_mirror
  x += dpp_term<0x140,0xF>(x);   // row_mirror
  x += dpp_term<0x142,0xA>(x);   // row_bcast15 -> rows 1,3
  x += dpp_term<0x143,0xC>(x);   // row_bcast31 -> rows 2,3
  return x;
}
__device__ __forceinline__ float wave_max63(float x) {
  x = fmaxf(x, dpp_term<0xB1, 0xF>(x));
  x = fmaxf(x, dpp_term<0x4E, 0xF>(x));
  x = fmaxf(x, dpp_term<0x141,0xF>(x));
  x = fmaxf(x, dpp_term<0x140,0xF>(x));
  x = fmaxf(x, dpp_term<0x142,0xA>(x));
  x = fmaxf(x, dpp_term<0x143,0xC>(x));
  return x;
}

// ---------- Kernel B: one wave per (n,c): box sums (avg) + global max (gfeat->cat)
//            masks/areas computed inline per wave (kA eliminated) ----------
__global__ __launch_bounds__(256) void kB(const float* __restrict__ x,
    const float* __restrict__ poses,
    float* __restrict__ avg, float* __restrict__ cat) {
  int gw   = (blockIdx.x << 2) | (threadIdx.x >> 6);  // 0 .. N*C-1
  int lane = threadIdx.x & 63;
  int n = gw >> 11;
  int c = gw & 2047;
  // inline box -> bitmask (exact reference op order, fp32; rintf == np.round)
  unsigned MH[P_], MW[P_];
  float INV[P_];
  const float* kpn = poses + (size_t)n * 68;   // 17*4
#pragma unroll
  for (int p = 0; p < P_; ++p) {
    const float* kp = kpn + 16 * p;            // pose row 4p
    float px = kp[0], py = kp[1], z = kp[2];
    float bx = fminf(fmaxf(px - 0.25f, 0.f), 0.75f) * z;
    float by = fminf(fmaxf(py - 0.25f, 0.f), 0.75f) * z;
    float bw = 0.5f * z;
    float bh = 0.5f * z;
    int xs = (int)fmaxf(0.f,  rintf(12.f * bx));
    int xe = (int)fminf(11.f, rintf(12.f * (bx + bw)));
    int ys = (int)fmaxf(0.f,  rintf(24.f * by));
    int ye = (int)fminf(23.f, rintf(24.f * (by + bh)));
    MH[p] = ((1u << ye) - 1u) & ~((1u << ys) - 1u);
    MW[p] = ((1u << xe) - 1u) & ~((1u << xs) - 1u);
    int area = (ye - ys) * (xe - xs);
    INV[p] = area > 0 ? 1.f / (float)area : 1.f;
  }
  const float4* xp = (const float4*)(x + (size_t)gw * HW_);
  float s[P_] = {0.f, 0.f, 0.f, 0.f, 0.f};
  float4 v = xp[lane];
  int e0 = lane << 2;
  int h  = e0 / 12;
  int w0 = e0 - h * 12;
  float mx = fmaxf(fmaxf(v.x, v.y), fmaxf(v.z, v.w));
#pragma unroll
  for (int p = 0; p < P_; ++p) {
    unsigned bits = (0u - ((MH[p] >> h) & 1u)) & (MW[p] >> w0);
    s[p] += (bits & 1u) ? v.x : 0.f;
    s[p] += (bits & 2u) ? v.y : 0.f;
    s[p] += (bits & 4u) ? v.z : 0.f;
    s[p] += (bits & 8u) ? v.w : 0.f;
  }
  if (lane < 8) {
    float4 v2 = xp[64 + lane];
    int e1 = 256 + (lane << 2);
    int h1 = e1 / 12;
    int w1 = e1 - h1 * 12;
    mx = fmaxf(mx, fmaxf(fmaxf(v2.x, v2.y), fmaxf(v2.z, v2.w)));
#pragma unroll
    for (int p = 0; p < P_; ++p) {
      unsigned bits = (0u - ((MH[p] >> h1) & 1u)) & (MW[p] >> w1);
      s[p] += (bits & 1u) ? v2.x : 0.f;
      s[p] += (bits & 2u) ? v2.y : 0.f;
      s[p] += (bits & 4u) ? v2.z : 0.f;
      s[p] += (bits & 8u) ? v2.w : 0.f;
    }
  }
  mx = wave_max63(mx);
#pragma unroll
  for (int p = 0; p < P_; ++p) s[p] = wave_sum63(s[p]);
  if (lane == 63) {
    cat[(size_t)n * CM_ + LOC_ + c] = mx;
#pragma unroll
    for (int p = 0; p < P_; ++p)
      avg[((size_t)n * P_ + p) * C_ + c] = s[p] * INV[p];
  }
}

// ---------- shared 64x64 fp32 tile GEMM over GSEG 64-chunks; register prefetch ----------
template<int GSEG>
__device__ __forceinline__ void gemm_tile(const float* __restrict__ Ag, int lda,
                                          const float* __restrict__ Wg, int ldw,
                                          float* __restrict__ Og, int ldo,
                                          float* As, float* Ws) {
  const int t  = threadIdx.x;
  const int nq = t & 15;          // output rows n = nq + 16*i
  const int kq = t >> 4;          // output cols k = kq + 16*j
  const int c4 = (t & 15) << 2;
  const int rr = t >> 4;
  float4 pA[4], pW[4];
#pragma unroll
  for (int i = 0; i < 4; ++i) {
    int r = rr + (i << 4);
    pA[i] = *(const float4*)&Ag[(size_t)r * lda + c4];
    pW[i] = *(const float4*)&Wg[(size_t)r * ldw + c4];
  }
  float acc[4][4] = {};
  for (int g = 0; g < GSEG; ++g) {
    __syncthreads();
#pragma unroll
    for (int i = 0; i < 4; ++i) {
      int r = rr + (i << 4);
      *(float4*)&As[r * 68 + c4] = pA[i];
      *(float4*)&Ws[r * 68 + c4] = pW[i];
    }
    __syncthreads();
    if (g + 1 < GSEG) {
#pragma unroll
      for (int i = 0; i < 4; ++i) {   // prefetch next stage; overlaps compute below
        int r = rr + (i << 4);
        pA[i] = *(const float4*)&Ag[(size_t)r * lda + ((g + 1) << 6) + c4];
        pW[i] = *(const float4*)&Wg[(size_t)r * ldw + ((g + 1) << 6) + c4];
      }
    }
#pragma unroll
    for (int c = 0; c < 64; c += 4) {
      float4 a[4], w[4];
#pragma unroll
      for (int i = 0; i < 4; ++i) a[i] = *(const float4*)&As[(nq + (i << 4)) * 68 + c];
#pragma unroll
      for (int j = 0; j < 4; ++j) w[j] = *(const float4*)&Ws[(kq + (j << 4)) * 68 + c];
#pragma unroll
      for (int i = 0; i < 4; ++i)
#pragma unroll
        for (int j = 0; j < 4; ++j)
          acc[i][j] += a[i].x * w[j].x + a[i].y * w[j].y + a[i].z * w[j].z + a[i].w * w[j].w;
    }
  }
#pragma unroll
  for (int i = 0; i < 4; ++i)
#pragma unroll
    for (int j = 0; j < 4; ++j)
      Og[(size_t)(nq + (i << 4)) * ldo + kq + (j << 4)] = acc[i][j];
}

// loc GEMM partials: avg(64x2048 per-p) x local_w[p]^T -> locP[seg][64][1280]
__global__ __launch_bounds__(256) void kC(const float* __restrict__ avg,
                                          const float* __restrict__ local_w,
                                          float* __restrict__ locP) {
  __shared__ float As[64 * 68];
  __shared__ float Ws[64 * 68];
  int b  = blockIdx.x;            // 160 = (5p * 4kt) tiles * 8 segs
  int tl = b >> 3;
  int sg = b & 7;
  int p  = tl >> 2;
  int kt = tl & 3;
  const float* Ag = avg + p * C_ + (sg << 8);
  const float* Wg = local_w + ((size_t)p * 256 + (kt << 6)) * C_ + (sg << 8);
  float* Og = locP + (size_t)sg * (N_ * LOC_) + (p << 8) + (kt << 6);
  gemm_tile<4>(Ag, P_ * C_, Wg, C_, Og, LOC_, As, Ws);
}

// reduce locP over segs + BN(recomputed fold) + ReLU -> cat[:, 0:1280]
__global__ __launch_bounds__(256) void kC2(const float* __restrict__ locP,
    const float* __restrict__ lb, const float* __restrict__ lg, const float* __restrict__ lbe,
    const float* __restrict__ lm, const float* __restrict__ lv,
    float* __restrict__ cat) {
  int i = blockIdx.x * 256 + threadIdx.x;   // < 64*1280
  int n = i / LOC_;
  int q = i - n * LOC_;
  float s = 0.f;
#pragma unroll
  for (int sg = 0; sg < SEGC; ++sg) s += locP[(size_t)sg * (N_ * LOC_) + i];
  float sc = lg[q] / sqrtf(lv[q] + 1e-5f);
  float v = (s + lb[q] - lm[q]) * sc + lbe[q];
  cat[(size_t)n * CM_ + q] = fmaxf(v, 0.f);
}

// merge GEMM partials: cat(64x3328) x merge_w^T -> mrgP[seg][64][2048]
__global__ __launch_bounds__(256) void kD(const float* __restrict__ cat,
                                          const float* __restrict__ merge_w,
                                          float* __restrict__ mrgP) {
  __shared__ float As[64 * 68];
  __shared__ float Ws[64 * 68];
  int b  = blockIdx.x;            // 416 = 32 jt * 13 segs
  int jt = b / SEGM;
  int sg = b - jt * SEGM;
  const float* Ag = cat + (sg << 8);
  const float* Wg = merge_w + (size_t)(jt << 6) * CM_ + (sg << 8);
  float* Og = mrgP + (size_t)sg * (N_ * C_) + (jt << 6);
  gemm_tile<4>(Ag, CM_, Wg, CM_, Og, C_, As, Ws);
}

// reduce mrgP over segs + BN(recomputed fold) + ReLU + L2 normalize -> d_out
__global__ __launch_bounds__(256) void kE(const float* __restrict__ mrgP,
    const float* __restrict__ mb, const float* __restrict__ mg, const float* __restrict__ mbe,
    const float* __restrict__ mm, const float* __restrict__ mv,
    float* __restrict__ out) {
  int n = blockIdx.x, t = threadIdx.x;
  float z[8]; float ss = 0.f;
#pragma unroll
  for (int r = 0; r < 8; ++r) {
    int j = t + (r << 8);
    float y = 0.f;
#pragma unroll
    for (int sg = 0; sg < SEGM; ++sg) y += mrgP[(size_t)sg * (N_ * C_) + (size_t)n * C_ + j];
    float sc = mg[j] / sqrtf(mv[j] + 1e-5f);
    float v = (y + mb[j] - mm[j]) * sc + mbe[j];
    v = fmaxf(v, 0.f);
    z[r] = v; ss += v * v;
  }
#pragma unroll
  for (int off = 32; off; off >>= 1) ss += __shfl_xor(ss, off, 64);
  __shared__ float red[4];
  if ((t & 63) == 0) red[t >> 6] = ss;
  __syncthreads();
  float tot = red[0] + red[1] + red[2] + red[3];
  float inv = 1.f / fmaxf(sqrtf(tot), 1e-12f);
#pragma unroll
  for (int r = 0; r < 8; ++r) out[(size_t)n * C_ + t + (r << 8)] = z[r] * inv;
}

extern "C" void kernel_launch(void* const* d_in, const int* in_sizes, int n_in,
                              void* d_out, int out_size, void* d_ws, size_t ws_size,
                              hipStream_t stream) {
  const float* x          = (const float*)d_in[0];
  const float* poses      = (const float*)d_in[1];
  const float* local_w    = (const float*)d_in[2];
  const float* local_b    = (const float*)d_in[3];
  const float* local_g    = (const float*)d_in[4];
  const float* local_be   = (const float*)d_in[5];
  const float* local_m    = (const float*)d_in[6];
  const float* local_v    = (const float*)d_in[7];
  const float* merge_w    = (const float*)d_in[8];
  const float* merge_b    = (const float*)d_in[9];
  const float* merge_g    = (const float*)d_in[10];
  const float* merge_be   = (const float*)d_in[11];
  const float* merge_m    = (const float*)d_in[12];
  const float* merge_v    = (const float*)d_in[13];

  float* ws   = (float*)d_ws;
  float* cat  = ws;                          // 64*3328           = 212992
  float* avg  = ws + 212992;                 // 64*5*2048         = 655360
  float* locP = ws + 868352;                 // 8 * 64*1280       = 655360
  float* mrgP = ws + 1523712;                // 13 * 64*2048      = 1703936

  kB<<<(N_ * C_) / 4, 256, 0, stream>>>(x, poses, avg, cat);
  kC<<<20 * SEGC, 256, 0, stream>>>(avg, local_w, locP);
  kC2<<<(N_ * LOC_) / 256, 256, 0, stream>>>(locP, local_b, local_g, local_be,
                                             local_m, local_v, cat);
  kD<<<32 * SEGM, 256, 0, stream>>>(cat, merge_w, mrgP);
  kE<<<N_, 256, 0, stream>>>(mrgP, merge_b, merge_g, merge_be, merge_m, merge_v,
                             (float*)d_out);
}

// Round 4
// 341.654 us; speedup vs baseline: 1.0967x; 1.0967x over previous
//
#include <hip/hip_runtime.h>

#define N_   64
#define C_   2048
#define HW_  288
#define P_   5
#define CM_  3328   // C_ + P_*256
#define LOC_ 1280   // P_*256
#define SEGC 8      // K segments for loc GEMM  (2048/256)
#define SEGM 13     // K segments for merge GEMM (3328/256)

#define PITCH 28    // LDS row pitch (floats) for 24-element chunks; 28c%32 cycles all 8 bank-groups

// ---------- Kernel B (transposed): one THREAD per channel ----------
// Block = 256 threads = 256 channels of one image n. x staged via LDS in
// 12 double-buffered chunks of 2 rows (24 elements). All mask logic is
// wave-uniform (same n, same (h,w) walk) -> scalar selects, no reductions.
__global__ __launch_bounds__(256) void kB(const float* __restrict__ x,
    const float* __restrict__ poses,
    float* __restrict__ avg, float* __restrict__ cat) {
  __shared__ float lds[2][256 * PITCH];
  const int t  = threadIdx.x;
  const int n  = blockIdx.x >> 3;
  const int cb = (blockIdx.x & 7) << 8;          // channel base
  const int chbase = n * C_ + cb;                // global channel of thread 0

  // box -> bitmask (exact reference op order, fp32; rintf == np.round)
  unsigned MH[P_], MW[P_];
  float INV[P_];
  const float* kpn = poses + (size_t)n * 68;
#pragma unroll
  for (int p = 0; p < P_; ++p) {
    const float* kp = kpn + 16 * p;
    float px = kp[0], py = kp[1], z = kp[2];
    float bx = fminf(fmaxf(px - 0.25f, 0.f), 0.75f) * z;
    float by = fminf(fmaxf(py - 0.25f, 0.f), 0.75f) * z;
    float bw = 0.5f * z;
    float bh = 0.5f * z;
    int xs = (int)fmaxf(0.f,  rintf(12.f * bx));
    int xe = (int)fminf(11.f, rintf(12.f * (bx + bw)));
    int ys = (int)fmaxf(0.f,  rintf(24.f * by));
    int ye = (int)fminf(23.f, rintf(24.f * (by + bh)));
    MH[p] = ((1u << ye) - 1u) & ~((1u << ys) - 1u);
    MW[p] = ((1u << xe) - 1u) & ~((1u << xs) - 1u);
    int area = (ye - ys) * (xe - xs);
    INV[p] = area > 0 ? 1.f / (float)area : 1.f;
  }

  const float4* x4 = (const float4*)x;
  // stage chunk ci (2 rows = 6 float4 per channel) into lds[db]
  auto stage = [&](int ci, int db) {
#pragma unroll
    for (int k = 0; k < 6; ++k) {
      unsigned flat = k * 256 + t;               // 0..1535
      unsigned cl = flat / 6u;
      unsigned j  = flat - 6u * cl;
      float4 v = x4[(size_t)(chbase + cl) * 72 + ci * 6 + j];
      *(float4*)&lds[db][cl * PITCH + 4 * j] = v;
    }
  };

  float s[P_] = {0.f, 0.f, 0.f, 0.f, 0.f};
  float mx = -3.402823466e+38f;

  stage(0, 0);
  __syncthreads();
  for (int ci = 0; ci < 12; ++ci) {
    if (ci + 1 < 12) stage(ci + 1, (ci + 1) & 1);
    const float* row = &lds[ci & 1][t * PITCH];
#pragma unroll
    for (int r = 0; r < 2; ++r) {
      int h = 2 * ci + r;
      float4 a = *(const float4*)(row + r * 12 + 0);
      float4 b = *(const float4*)(row + r * 12 + 4);
      float4 c = *(const float4*)(row + r * 12 + 8);
      float m1 = fmaxf(fmaxf(a.x, a.y), fmaxf(a.z, a.w));
      float m2 = fmaxf(fmaxf(b.x, b.y), fmaxf(b.z, b.w));
      float m3 = fmaxf(fmaxf(c.x, c.y), fmaxf(c.z, c.w));
      mx = fmaxf(mx, fmaxf(m1, fmaxf(m2, m3)));
#pragma unroll
      for (int p = 0; p < P_; ++p) {
        unsigned cm = ((MH[p] >> h) & 1u) ? MW[p] : 0u;   // wave-uniform
        if (cm) {
          float t0 = ((cm & 0x001u) ? a.x : 0.f) + ((cm & 0x002u) ? a.y : 0.f);
          float t1 = ((cm & 0x004u) ? a.z : 0.f) + ((cm & 0x008u) ? a.w : 0.f);
          float t2 = ((cm & 0x010u) ? b.x : 0.f) + ((cm & 0x020u) ? b.y : 0.f);
          float t3 = ((cm & 0x040u) ? b.z : 0.f) + ((cm & 0x080u) ? b.w : 0.f);
          float t4 = ((cm & 0x100u) ? c.x : 0.f) + ((cm & 0x200u) ? c.y : 0.f);
          float t5 = ((cm & 0x400u) ? c.z : 0.f) + ((cm & 0x800u) ? c.w : 0.f);
          s[p] += ((t0 + t1) + (t2 + t3)) + (t4 + t5);
        }
      }
    }
    __syncthreads();
  }

  int c = cb + t;
  cat[(size_t)n * CM_ + LOC_ + c] = mx;
#pragma unroll
  for (int p = 0; p < P_; ++p)
    avg[((size_t)n * P_ + p) * C_ + c] = s[p] * INV[p];
}

// ---------- shared 64x64 fp32 tile GEMM over GSEG 64-chunks; register prefetch ----------
template<int GSEG>
__device__ __forceinline__ void gemm_tile(const float* __restrict__ Ag, int lda,
                                          const float* __restrict__ Wg, int ldw,
                                          float* __restrict__ Og, int ldo,
                                          float* As, float* Ws) {
  const int t  = threadIdx.x;
  const int nq = t & 15;          // output rows n = nq + 16*i
  const int kq = t >> 4;          // output cols k = kq + 16*j
  const int c4 = (t & 15) << 2;
  const int rr = t >> 4;
  float4 pA[4], pW[4];
#pragma unroll
  for (int i = 0; i < 4; ++i) {
    int r = rr + (i << 4);
    pA[i] = *(const float4*)&Ag[(size_t)r * lda + c4];
    pW[i] = *(const float4*)&Wg[(size_t)r * ldw + c4];
  }
  float acc[4][4] = {};
  for (int g = 0; g < GSEG; ++g) {
    __syncthreads();
#pragma unroll
    for (int i = 0; i < 4; ++i) {
      int r = rr + (i << 4);
      *(float4*)&As[r * 68 + c4] = pA[i];
      *(float4*)&Ws[r * 68 + c4] = pW[i];
    }
    __syncthreads();
    if (g + 1 < GSEG) {
#pragma unroll
      for (int i = 0; i < 4; ++i) {   // prefetch next stage; overlaps compute below
        int r = rr + (i << 4);
        pA[i] = *(const float4*)&Ag[(size_t)r * lda + ((g + 1) << 6) + c4];
        pW[i] = *(const float4*)&Wg[(size_t)r * ldw + ((g + 1) << 6) + c4];
      }
    }
#pragma unroll
    for (int c = 0; c < 64; c += 4) {
      float4 a[4], w[4];
#pragma unroll
      for (int i = 0; i < 4; ++i) a[i] = *(const float4*)&As[(nq + (i << 4)) * 68 + c];
#pragma unroll
      for (int j = 0; j < 4; ++j) w[j] = *(const float4*)&Ws[(kq + (j << 4)) * 68 + c];
#pragma unroll
      for (int i = 0; i < 4; ++i)
#pragma unroll
        for (int j = 0; j < 4; ++j)
          acc[i][j] += a[i].x * w[j].x + a[i].y * w[j].y + a[i].z * w[j].z + a[i].w * w[j].w;
    }
  }
#pragma unroll
  for (int i = 0; i < 4; ++i)
#pragma unroll
    for (int j = 0; j < 4; ++j)
      Og[(size_t)(nq + (i << 4)) * ldo + kq + (j << 4)] = acc[i][j];
}

// loc GEMM partials: avg(64x2048 per-p) x local_w[p]^T -> locP[seg][64][1280]
__global__ __launch_bounds__(256) void kC(const float* __restrict__ avg,
                                          const float* __restrict__ local_w,
                                          float* __restrict__ locP) {
  __shared__ float As[64 * 68];
  __shared__ float Ws[64 * 68];
  int b  = blockIdx.x;            // 160 = (5p * 4kt) tiles * 8 segs
  int tl = b >> 3;
  int sg = b & 7;
  int p  = tl >> 2;
  int kt = tl & 3;
  const float* Ag = avg + p * C_ + (sg << 8);
  const float* Wg = local_w + ((size_t)p * 256 + (kt << 6)) * C_ + (sg << 8);
  float* Og = locP + (size_t)sg * (N_ * LOC_) + (p << 8) + (kt << 6);
  gemm_tile<4>(Ag, P_ * C_, Wg, C_, Og, LOC_, As, Ws);
}

// reduce locP over segs + BN(recomputed fold) + ReLU -> cat[:, 0:1280]
__global__ __launch_bounds__(256) void kC2(const float* __restrict__ locP,
    const float* __restrict__ lb, const float* __restrict__ lg, const float* __restrict__ lbe,
    const float* __restrict__ lm, const float* __restrict__ lv,
    float* __restrict__ cat) {
  int i = blockIdx.x * 256 + threadIdx.x;   // < 64*1280
  int n = i / LOC_;
  int q = i - n * LOC_;
  float s = 0.f;
#pragma unroll
  for (int sg = 0; sg < SEGC; ++sg) s += locP[(size_t)sg * (N_ * LOC_) + i];
  float sc = lg[q] / sqrtf(lv[q] + 1e-5f);
  float v = (s + lb[q] - lm[q]) * sc + lbe[q];
  cat[(size_t)n * CM_ + q] = fmaxf(v, 0.f);
}

// merge GEMM partials: cat(64x3328) x merge_w^T -> mrgP[seg][64][2048]
__global__ __launch_bounds__(256) void kD(const float* __restrict__ cat,
                                          const float* __restrict__ merge_w,
                                          float* __restrict__ mrgP) {
  __shared__ float As[64 * 68];
  __shared__ float Ws[64 * 68];
  int b  = blockIdx.x;            // 416 = 32 jt * 13 segs
  int jt = b / SEGM;
  int sg = b - jt * SEGM;
  const float* Ag = cat + (sg << 8);
  const float* Wg = merge_w + (size_t)(jt << 6) * CM_ + (sg << 8);
  float* Og = mrgP + (size_t)sg * (N_ * C_) + (jt << 6);
  gemm_tile<4>(Ag, CM_, Wg, CM_, Og, C_, As, Ws);
}

// reduce mrgP over segs + BN(recomputed fold) + ReLU + L2 normalize -> d_out
__global__ __launch_bounds__(256) void kE(const float* __restrict__ mrgP,
    const float* __restrict__ mb, const float* __restrict__ mg, const float* __restrict__ mbe,
    const float* __restrict__ mm, const float* __restrict__ mv,
    float* __restrict__ out) {
  int n = blockIdx.x, t = threadIdx.x;
  float z[8]; float ss = 0.f;
#pragma unroll
  for (int r = 0; r < 8; ++r) {
    int j = t + (r << 8);
    float y = 0.f;
#pragma unroll
    for (int sg = 0; sg < SEGM; ++sg) y += mrgP[(size_t)sg * (N_ * C_) + (size_t)n * C_ + j];
    float sc = mg[j] / sqrtf(mv[j] + 1e-5f);
    float v = (y + mb[j] - mm[j]) * sc + mbe[j];
    v = fmaxf(v, 0.f);
    z[r] = v; ss += v * v;
  }
#pragma unroll
  for (int off = 32; off; off >>= 1) ss += __shfl_xor(ss, off, 64);
  __shared__ float red[4];
  if ((t & 63) == 0) red[t >> 6] = ss;
  __syncthreads();
  float tot = red[0] + red[1] + red[2] + red[3];
  float inv = 1.f / fmaxf(sqrtf(tot), 1e-12f);
#pragma unroll
  for (int r = 0; r < 8; ++r) out[(size_t)n * C_ + t + (r << 8)] = z[r] * inv;
}

extern "C" void kernel_launch(void* const* d_in, const int* in_sizes, int n_in,
                              void* d_out, int out_size, void* d_ws, size_t ws_size,
                              hipStream_t stream) {
  const float* x          = (const float*)d_in[0];
  const float* poses      = (const float*)d_in[1];
  const float* local_w    = (const float*)d_in[2];
  const float* local_b    = (const float*)d_in[3];
  const float* local_g    = (const float*)d_in[4];
  const float* local_be   = (const float*)d_in[5];
  const float* local_m    = (const float*)d_in[6];
  const float* local_v    = (const float*)d_in[7];
  const float* merge_w    = (const float*)d_in[8];
  const float* merge_b    = (const float*)d_in[9];
  const float* merge_g    = (const float*)d_in[10];
  const float* merge_be   = (const float*)d_in[11];
  const float* merge_m    = (const float*)d_in[12];
  const float* merge_v    = (const float*)d_in[13];

  float* ws   = (float*)d_ws;
  float* cat  = ws;                          // 64*3328           = 212992
  float* avg  = ws + 212992;                 // 64*5*2048         = 655360
  float* locP = ws + 868352;                 // 8 * 64*1280       = 655360
  float* mrgP = ws + 1523712;                // 13 * 64*2048      = 1703936

  kB<<<512, 256, 0, stream>>>(x, poses, avg, cat);
  kC<<<20 * SEGC, 256, 0, stream>>>(avg, local_w, locP);
  kC2<<<(N_ * LOC_) / 256, 256, 0, stream>>>(locP, local_b, local_g, local_be,
                                             local_m, local_v, cat);
  kD<<<32 * SEGM, 256, 0, stream>>>(cat, merge_w, mrgP);
  kE<<<N_, 256, 0, stream>>>(mrgP, merge_b, merge_g, merge_be, merge_m, merge_v,
                             (float*)d_out);
}

// Round 5
// 335.234 us; speedup vs baseline: 1.1177x; 1.0192x over previous
//
#include <hip/hip_runtime.h>

#define N_   64
#define C_   2048
#define HW_  288
#define P_   5
#define CM_  3328   // C_ + P_*256
#define LOC_ 1280   // P_*256
#define SEGC 8      // K segments for loc GEMM  (2048/256)
#define SEGM 13     // K segments for merge GEMM (3328/256)

#define PITCH 28    // LDS row pitch (floats); stride 28 mod 32 -> 8 distinct 4-bank windows per octet (conflict-free b128)

// ---------- Kernel B (transposed): one THREAD per channel ----------
// Block = 256 threads = 256 channels of one image n. x staged through LDS in
// 12 double-buffered chunks of 2 rows (24 elems/channel). Pipeline order is
// load(ci+1)->regs, compute(ci) from LDS, regs->LDS, barrier — so the global
// vmcnt wait lands AFTER compute and the HBM latency is hidden.
__global__ __launch_bounds__(256) void kB(const float* __restrict__ x,
    const float* __restrict__ poses,
    float* __restrict__ avg, float* __restrict__ cat) {
  __shared__ float lds[2][256 * PITCH];
  const int t  = threadIdx.x;
  const int n  = blockIdx.x >> 3;
  const int cb = (blockIdx.x & 7) << 8;          // channel base
  const int chbase = n * C_ + cb;                // global channel of thread 0

  // box -> bitmask (exact reference op order, fp32; rintf == np.round)
  unsigned MH[P_], MW[P_];
  float INV[P_];
  const float* kpn = poses + (size_t)n * 68;
#pragma unroll
  for (int p = 0; p < P_; ++p) {
    const float* kp = kpn + 16 * p;
    float px = kp[0], py = kp[1], z = kp[2];
    float bx = fminf(fmaxf(px - 0.25f, 0.f), 0.75f) * z;
    float by = fminf(fmaxf(py - 0.25f, 0.f), 0.75f) * z;
    float bw = 0.5f * z;
    float bh = 0.5f * z;
    int xs = (int)fmaxf(0.f,  rintf(12.f * bx));
    int xe = (int)fminf(11.f, rintf(12.f * (bx + bw)));
    int ys = (int)fmaxf(0.f,  rintf(24.f * by));
    int ye = (int)fminf(23.f, rintf(24.f * (by + bh)));
    MH[p] = ((1u << ye) - 1u) & ~((1u << ys) - 1u);
    MW[p] = ((1u << xe) - 1u) & ~((1u << xs) - 1u);
    int area = (ye - ys) * (xe - xs);
    INV[p] = area > 0 ? 1.f / (float)area : 1.f;
  }

  const float4* x4 = (const float4*)x;
  // per-thread staging slots: flat = k*256+t -> (channel cl, float4 j within chunk)
  size_t gbase[6];
  int    loff[6];
#pragma unroll
  for (int k = 0; k < 6; ++k) {
    unsigned flat = k * 256 + t;                 // 0..1535
    unsigned cl = flat / 6u;
    unsigned j  = flat - 6u * cl;
    gbase[k] = (size_t)(chbase + cl) * 72 + j;   // float4 index; + ci*6 per chunk
    loff[k]  = cl * PITCH + 4 * j;
  }

  float4 rg[6];
  auto loadRegs = [&](int ci) {
#pragma unroll
    for (int k = 0; k < 6; ++k) rg[k] = x4[gbase[k] + ci * 6];
  };
  auto writeRegs = [&](int db) {
#pragma unroll
    for (int k = 0; k < 6; ++k) *(float4*)&lds[db][loff[k]] = rg[k];
  };

  float s[P_] = {0.f, 0.f, 0.f, 0.f, 0.f};
  float mx = -3.402823466e+38f;

  loadRegs(0);
  writeRegs(0);
  __syncthreads();
  for (int ci = 0; ci < 12; ++ci) {
    if (ci + 1 < 12) loadRegs(ci + 1);           // issue global loads (no wait yet)
    const float* row = &lds[ci & 1][t * PITCH];
#pragma unroll
    for (int r = 0; r < 2; ++r) {
      int h = 2 * ci + r;
      float4 a = *(const float4*)(row + r * 12 + 0);
      float4 b = *(const float4*)(row + r * 12 + 4);
      float4 c = *(const float4*)(row + r * 12 + 8);
      float m1 = fmaxf(fmaxf(a.x, a.y), fmaxf(a.z, a.w));
      float m2 = fmaxf(fmaxf(b.x, b.y), fmaxf(b.z, b.w));
      float m3 = fmaxf(fmaxf(c.x, c.y), fmaxf(c.z, c.w));
      mx = fmaxf(mx, fmaxf(m1, fmaxf(m2, m3)));
#pragma unroll
      for (int p = 0; p < P_; ++p) {
        unsigned cm = ((MH[p] >> h) & 1u) ? MW[p] : 0u;   // wave-uniform
        if (cm) {
          float t0 = ((cm & 0x001u) ? a.x : 0.f) + ((cm & 0x002u) ? a.y : 0.f);
          float t1 = ((cm & 0x004u) ? a.z : 0.f) + ((cm & 0x008u) ? a.w : 0.f);
          float t2 = ((cm & 0x010u) ? b.x : 0.f) + ((cm & 0x020u) ? b.y : 0.f);
          float t3 = ((cm & 0x040u) ? b.z : 0.f) + ((cm & 0x080u) ? b.w : 0.f);
          float t4 = ((cm & 0x100u) ? c.x : 0.f) + ((cm & 0x200u) ? c.y : 0.f);
          float t5 = ((cm & 0x400u) ? c.z : 0.f) + ((cm & 0x800u) ? c.w : 0.f);
          s[p] += ((t0 + t1) + (t2 + t3)) + (t4 + t5);
        }
      }
    }
    if (ci + 1 < 12) {
      writeRegs((ci + 1) & 1);                   // vmcnt wait lands here, after compute
      __syncthreads();
    }
  }

  int c = cb + t;
  cat[(size_t)n * CM_ + LOC_ + c] = mx;
#pragma unroll
  for (int p = 0; p < P_; ++p)
    avg[((size_t)n * P_ + p) * C_ + c] = s[p] * INV[p];
}

// ---------- shared 64x64 fp32 tile GEMM over GSEG 64-chunks of K; plain stores
//            (r2 version: no register prefetch — keeps VGPR ~164, 3 waves/SIMD) ----------
template<int GSEG>
__device__ __forceinline__ void gemm_tile(const float* __restrict__ Ag, int lda,
                                          const float* __restrict__ Wg, int ldw,
                                          float* __restrict__ Og, int ldo,
                                          float* As, float* Ws) {
  const int t  = threadIdx.x;
  const int nq = t & 15;          // output rows n = nq + 16*i
  const int kq = t >> 4;          // output cols k = kq + 16*j
  const int c4 = (t & 15) << 2;
  const int rr = t >> 4;
  float acc[4][4] = {};
  for (int g = 0; g < GSEG; ++g) {
    __syncthreads();
#pragma unroll
    for (int i = 0; i < 4; ++i) {
      int r = rr + (i << 4);
      *(float4*)&As[r * 68 + c4] = *(const float4*)&Ag[(size_t)r * lda + (g << 6) + c4];
      *(float4*)&Ws[r * 68 + c4] = *(const float4*)&Wg[(size_t)r * ldw + (g << 6) + c4];
    }
    __syncthreads();
#pragma unroll
    for (int c = 0; c < 64; c += 4) {
      float4 a[4], w[4];
#pragma unroll
      for (int i = 0; i < 4; ++i) a[i] = *(const float4*)&As[(nq + (i << 4)) * 68 + c];
#pragma unroll
      for (int j = 0; j < 4; ++j) w[j] = *(const float4*)&Ws[(kq + (j << 4)) * 68 + c];
#pragma unroll
      for (int i = 0; i < 4; ++i)
#pragma unroll
        for (int j = 0; j < 4; ++j)
          acc[i][j] += a[i].x * w[j].x + a[i].y * w[j].y + a[i].z * w[j].z + a[i].w * w[j].w;
    }
  }
#pragma unroll
  for (int i = 0; i < 4; ++i)
#pragma unroll
    for (int j = 0; j < 4; ++j)
      Og[(size_t)(nq + (i << 4)) * ldo + kq + (j << 4)] = acc[i][j];
}

// loc GEMM partials: avg(64x2048 per-p) x local_w[p]^T -> locP[seg][64][1280]
__global__ __launch_bounds__(256) void kC(const float* __restrict__ avg,
                                          const float* __restrict__ local_w,
                                          float* __restrict__ locP) {
  __shared__ float As[64 * 68];
  __shared__ float Ws[64 * 68];
  int b  = blockIdx.x;            // 160 = (5p * 4kt) tiles * 8 segs
  int tl = b >> 3;
  int sg = b & 7;
  int p  = tl >> 2;
  int kt = tl & 3;
  const float* Ag = avg + p * C_ + (sg << 8);
  const float* Wg = local_w + ((size_t)p * 256 + (kt << 6)) * C_ + (sg << 8);
  float* Og = locP + (size_t)sg * (N_ * LOC_) + (p << 8) + (kt << 6);
  gemm_tile<4>(Ag, P_ * C_, Wg, C_, Og, LOC_, As, Ws);
}

// reduce locP over segs + BN(recomputed fold) + ReLU -> cat[:, 0:1280]
__global__ __launch_bounds__(256) void kC2(const float* __restrict__ locP,
    const float* __restrict__ lb, const float* __restrict__ lg, const float* __restrict__ lbe,
    const float* __restrict__ lm, const float* __restrict__ lv,
    float* __restrict__ cat) {
  int i = blockIdx.x * 256 + threadIdx.x;   // < 64*1280
  int n = i / LOC_;
  int q = i - n * LOC_;
  float s = 0.f;
#pragma unroll
  for (int sg = 0; sg < SEGC; ++sg) s += locP[(size_t)sg * (N_ * LOC_) + i];
  float sc = lg[q] / sqrtf(lv[q] + 1e-5f);
  float v = (s + lb[q] - lm[q]) * sc + lbe[q];
  cat[(size_t)n * CM_ + q] = fmaxf(v, 0.f);
}

// merge GEMM partials: cat(64x3328) x merge_w^T -> mrgP[seg][64][2048]
__global__ __launch_bounds__(256) void kD(const float* __restrict__ cat,
                                          const float* __restrict__ merge_w,
                                          float* __restrict__ mrgP) {
  __shared__ float As[64 * 68];
  __shared__ float Ws[64 * 68];
  int b  = blockIdx.x;            // 416 = 32 jt * 13 segs
  int jt = b / SEGM;
  int sg = b - jt * SEGM;
  const float* Ag = cat + (sg << 8);
  const float* Wg = merge_w + (size_t)(jt << 6) * CM_ + (sg << 8);
  float* Og = mrgP + (size_t)sg * (N_ * C_) + (jt << 6);
  gemm_tile<4>(Ag, CM_, Wg, CM_, Og, C_, As, Ws);
}

// reduce mrgP over segs + BN(recomputed fold) + ReLU + L2 normalize -> d_out
__global__ __launch_bounds__(256) void kE(const float* __restrict__ mrgP,
    const float* __restrict__ mb, const float* __restrict__ mg, const float* __restrict__ mbe,
    const float* __restrict__ mm, const float* __restrict__ mv,
    float* __restrict__ out) {
  int n = blockIdx.x, t = threadIdx.x;
  float z[8]; float ss = 0.f;
#pragma unroll
  for (int r = 0; r < 8; ++r) {
    int j = t + (r << 8);
    float y = 0.f;
#pragma unroll
    for (int sg = 0; sg < SEGM; ++sg) y += mrgP[(size_t)sg * (N_ * C_) + (size_t)n * C_ + j];
    float sc = mg[j] / sqrtf(mv[j] + 1e-5f);
    float v = (y + mb[j] - mm[j]) * sc + mbe[j];
    v = fmaxf(v, 0.f);
    z[r] = v; ss += v * v;
  }
#pragma unroll
  for (int off = 32; off; off >>= 1) ss += __shfl_xor(ss, off, 64);
  __shared__ float red[4];
  if ((t & 63) == 0) red[t >> 6] = ss;
  __syncthreads();
  float tot = red[0] + red[1] + red[2] + red[3];
  float inv = 1.f / fmaxf(sqrtf(tot), 1e-12f);
#pragma unroll
  for (int r = 0; r < 8; ++r) out[(size_t)n * C_ + t + (r << 8)] = z[r] * inv;
}

extern "C" void kernel_launch(void* const* d_in, const int* in_sizes, int n_in,
                              void* d_out, int out_size, void* d_ws, size_t ws_size,
                              hipStream_t stream) {
  const float* x          = (const float*)d_in[0];
  const float* poses      = (const float*)d_in[1];
  const float* local_w    = (const float*)d_in[2];
  const float* local_b    = (const float*)d_in[3];
  const float* local_g    = (const float*)d_in[4];
  const float* local_be   = (const float*)d_in[5];
  const float* local_m    = (const float*)d_in[6];
  const float* local_v    = (const float*)d_in[7];
  const float* merge_w    = (const float*)d_in[8];
  const float* merge_b    = (const float*)d_in[9];
  const float* merge_g    = (const float*)d_in[10];
  const float* merge_be   = (const float*)d_in[11];
  const float* merge_m    = (const float*)d_in[12];
  const float* merge_v    = (const float*)d_in[13];

  float* ws   = (float*)d_ws;
  float* cat  = ws;                          // 64*3328           = 212992
  float* avg  = ws + 212992;                 // 64*5*2048         = 655360
  float* locP = ws + 868352;                 // 8 * 64*1280       = 655360
  float* mrgP = ws + 1523712;                // 13 * 64*2048      = 1703936

  kB<<<512, 256, 0, stream>>>(x, poses, avg, cat);
  kC<<<20 * SEGC, 256, 0, stream>>>(avg, local_w, locP);
  kC2<<<(N_ * LOC_) / 256, 256, 0, stream>>>(locP, local_b, local_g, local_be,
                                             local_m, local_v, cat);
  kD<<<32 * SEGM, 256, 0, stream>>>(cat, merge_w, mrgP);
  kE<<<N_, 256, 0, stream>>>(mrgP, merge_b, merge_g, merge_be, merge_m, merge_v,
                             (float*)d_out);
}

// Round 6
// 294.746 us; speedup vs baseline: 1.2712x; 1.1374x over previous
//
#include <hip/hip_runtime.h>

#define N_   64
#define C_   2048
#define HW_  288
#define P_   5
#define CM_  3328   // C_ + P_*256
#define LOC_ 1280   // P_*256
#define SEGC 8      // K segments for loc GEMM  (2048/256)
#define SEGM 13     // K segments for merge GEMM (3328/256)

#define PITCH  28   // kB LDS row pitch (floats): conflict-free b128
#define WPITCH 72   // GEMM LDS tile pitch (bf16): 36 dwords -> <=2-way (free)

typedef __attribute__((ext_vector_type(8))) short bf16x8;
typedef __attribute__((ext_vector_type(4))) float f32x4;

__device__ __forceinline__ unsigned short f2bf(float f) {   // fp32 -> bf16 RNE
  unsigned u = __float_as_uint(f);
  u = (u + 0x7FFFu + ((u >> 16) & 1u)) >> 16;
  return (unsigned short)u;
}
__device__ __forceinline__ unsigned pack2(float lo, float hi) {
  return (unsigned)f2bf(lo) | ((unsigned)f2bf(hi) << 16);
}

// ---------- Kernel B: one THREAD per channel; x staged via double-buffered LDS.
// Outputs avgB (bf16) and the gfeat region of catB (bf16). ----------
__global__ __launch_bounds__(256) void kB(const float* __restrict__ x,
    const float* __restrict__ poses,
    unsigned short* __restrict__ avgB, unsigned short* __restrict__ catB) {
  __shared__ float lds[2][256 * PITCH];
  const int t  = threadIdx.x;
  const int n  = blockIdx.x >> 3;
  const int cb = (blockIdx.x & 7) << 8;          // channel base
  const int chbase = n * C_ + cb;

  // box -> bitmask (exact reference op order, fp32; rintf == np.round)
  unsigned MH[P_], MW[P_];
  float INV[P_];
  const float* kpn = poses + (size_t)n * 68;
#pragma unroll
  for (int p = 0; p < P_; ++p) {
    const float* kp = kpn + 16 * p;
    float px = kp[0], py = kp[1], z = kp[2];
    float bx = fminf(fmaxf(px - 0.25f, 0.f), 0.75f) * z;
    float by = fminf(fmaxf(py - 0.25f, 0.f), 0.75f) * z;
    float bw = 0.5f * z;
    float bh = 0.5f * z;
    int xs = (int)fmaxf(0.f,  rintf(12.f * bx));
    int xe = (int)fminf(11.f, rintf(12.f * (bx + bw)));
    int ys = (int)fmaxf(0.f,  rintf(24.f * by));
    int ye = (int)fminf(23.f, rintf(24.f * (by + bh)));
    MH[p] = ((1u << ye) - 1u) & ~((1u << ys) - 1u);
    MW[p] = ((1u << xe) - 1u) & ~((1u << xs) - 1u);
    int area = (ye - ys) * (xe - xs);
    INV[p] = area > 0 ? 1.f / (float)area : 1.f;
  }

  const float4* x4 = (const float4*)x;
  size_t gbase[6];
  int    loff[6];
#pragma unroll
  for (int k = 0; k < 6; ++k) {
    unsigned flat = k * 256 + t;                 // 0..1535
    unsigned cl = flat / 6u;
    unsigned j  = flat - 6u * cl;
    gbase[k] = (size_t)(chbase + cl) * 72 + j;   // float4 idx; + ci*6 per chunk
    loff[k]  = cl * PITCH + 4 * j;
  }

  float4 rg[6];
  auto loadRegs = [&](int ci) {
#pragma unroll
    for (int k = 0; k < 6; ++k) rg[k] = x4[gbase[k] + ci * 6];
  };
  auto writeRegs = [&](int db) {
#pragma unroll
    for (int k = 0; k < 6; ++k) *(float4*)&lds[db][loff[k]] = rg[k];
  };

  float s[P_] = {0.f, 0.f, 0.f, 0.f, 0.f};
  float mx = -3.402823466e+38f;

  loadRegs(0);
  writeRegs(0);
  __syncthreads();
  for (int ci = 0; ci < 12; ++ci) {
    if (ci + 1 < 12) loadRegs(ci + 1);           // issue loads; wait lands after compute
    const float* row = &lds[ci & 1][t * PITCH];
#pragma unroll
    for (int r = 0; r < 2; ++r) {
      int h = 2 * ci + r;
      float4 a = *(const float4*)(row + r * 12 + 0);
      float4 b = *(const float4*)(row + r * 12 + 4);
      float4 c = *(const float4*)(row + r * 12 + 8);
      float m1 = fmaxf(fmaxf(a.x, a.y), fmaxf(a.z, a.w));
      float m2 = fmaxf(fmaxf(b.x, b.y), fmaxf(b.z, b.w));
      float m3 = fmaxf(fmaxf(c.x, c.y), fmaxf(c.z, c.w));
      mx = fmaxf(mx, fmaxf(m1, fmaxf(m2, m3)));
#pragma unroll
      for (int p = 0; p < P_; ++p) {
        unsigned cm = ((MH[p] >> h) & 1u) ? MW[p] : 0u;   // wave-uniform
        if (cm) {
          float t0 = ((cm & 0x001u) ? a.x : 0.f) + ((cm & 0x002u) ? a.y : 0.f);
          float t1 = ((cm & 0x004u) ? a.z : 0.f) + ((cm & 0x008u) ? a.w : 0.f);
          float t2 = ((cm & 0x010u) ? b.x : 0.f) + ((cm & 0x020u) ? b.y : 0.f);
          float t3 = ((cm & 0x040u) ? b.z : 0.f) + ((cm & 0x080u) ? b.w : 0.f);
          float t4 = ((cm & 0x100u) ? c.x : 0.f) + ((cm & 0x200u) ? c.y : 0.f);
          float t5 = ((cm & 0x400u) ? c.z : 0.f) + ((cm & 0x800u) ? c.w : 0.f);
          s[p] += ((t0 + t1) + (t2 + t3)) + (t4 + t5);
        }
      }
    }
    if (ci + 1 < 12) {
      writeRegs((ci + 1) & 1);
      __syncthreads();
    }
  }

  int c = cb + t;
  catB[(size_t)n * CM_ + LOC_ + c] = f2bf(mx);
#pragma unroll
  for (int p = 0; p < P_; ++p)
    avgB[((size_t)n * 5 + p) * C_ + c] = f2bf(s[p] * INV[p]);
}

// ---------- MFMA 64x64 tile over one 256-wide K segment.
// A (bf16, staged as-is), W (fp32, converted to bf16 during staging).
// aRow: uint4* at [row][seg k-base], advancing 8 uint4 (64 bf16) per g-chunk.
// wRow: float4* at [row][seg k-base], advancing 16 float4 (64 f32) per g-chunk.
__device__ __forceinline__ void mfma_seg(const uint4* __restrict__ aRow,
                                         const float4* __restrict__ wRow,
                                         unsigned short* As, unsigned short* Ws,
                                         f32x4 acc[4]) {
  const int t  = threadIdx.x;
  const int kq = t & 3;
  const int row = t >> 2;
  const int w  = t >> 6;
  const int l  = t & 63;
  unsigned short* aw = &As[row * WPITCH + kq * 16];
  unsigned short* ww = &Ws[row * WPITCH + kq * 16];
  const int arow16 = (16 * w + (l & 15)) * WPITCH + (l >> 4) * 8;
  const int brow16 = (l & 15) * WPITCH + (l >> 4) * 8;
  for (int g = 0; g < 4; ++g) {
    uint4 a0 = aRow[g * 8 + 0], a1 = aRow[g * 8 + 1];
    float4 w0 = wRow[g * 16 + 0], w1 = wRow[g * 16 + 1],
           w2 = wRow[g * 16 + 2], w3 = wRow[g * 16 + 3];
    uint4 pw0, pw1;
    pw0.x = pack2(w0.x, w0.y); pw0.y = pack2(w0.z, w0.w);
    pw0.z = pack2(w1.x, w1.y); pw0.w = pack2(w1.z, w1.w);
    pw1.x = pack2(w2.x, w2.y); pw1.y = pack2(w2.z, w2.w);
    pw1.z = pack2(w3.x, w3.y); pw1.w = pack2(w3.z, w3.w);
    if (g) __syncthreads();                       // prev mfma reads done
    *(uint4*)aw = a0; *(uint4*)(aw + 8) = a1;
    *(uint4*)ww = pw0; *(uint4*)(ww + 8) = pw1;
    __syncthreads();
#pragma unroll
    for (int s = 0; s < 2; ++s) {
      bf16x8 af = *(const bf16x8*)&As[arow16 + s * 32];
#pragma unroll
      for (int jm = 0; jm < 4; ++jm) {
        bf16x8 bf = *(const bf16x8*)&Ws[jm * 16 * WPITCH + brow16 + s * 32];
        acc[jm] = __builtin_amdgcn_mfma_f32_16x16x32_bf16(af, bf, acc[jm], 0, 0, 0);
      }
    }
  }
}

// loc GEMM partials: avgB(bf16) x local_w[p]^T -> locP[seg][64][1280] (f32)
__global__ __launch_bounds__(256) void kC(const unsigned short* __restrict__ avgB,
                                          const float* __restrict__ local_w,
                                          float* __restrict__ locP) {
  __shared__ unsigned short As[64 * WPITCH];
  __shared__ unsigned short Ws[64 * WPITCH];
  int b  = blockIdx.x;            // 160 = 5p * 4kt * 8sg
  int p  = b >> 5;
  int kt = (b >> 3) & 3;
  int sg = b & 7;
  const int t = threadIdx.x, row = t >> 2, kq = t & 3, w = t >> 6, l = t & 63;
  const uint4*  aRow = (const uint4*)avgB + ((size_t)row * 5 + p) * 256 + sg * 32 + kq * 2;
  const float4* wRow = (const float4*)(local_w + ((size_t)p * 256 + kt * 64 + row) * C_
                                       + sg * 256 + kq * 16);
  f32x4 acc[4] = {{0,0,0,0},{0,0,0,0},{0,0,0,0},{0,0,0,0}};
  mfma_seg(aRow, wRow, As, Ws, acc);
  float* outp = locP + (size_t)sg * (N_ * LOC_);
#pragma unroll
  for (int jm = 0; jm < 4; ++jm)
#pragma unroll
    for (int r = 0; r < 4; ++r)
      outp[(size_t)(16 * w + (l >> 4) * 4 + r) * LOC_ + p * 256 + kt * 64 + jm * 16 + (l & 15)]
        = acc[jm][r];
}

// reduce locP over segs + BN + ReLU -> catB[:, 0:1280] (bf16)
__global__ __launch_bounds__(256) void kC2(const float* __restrict__ locP,
    const float* __restrict__ lb, const float* __restrict__ lg, const float* __restrict__ lbe,
    const float* __restrict__ lm, const float* __restrict__ lv,
    unsigned short* __restrict__ catB) {
  int i = blockIdx.x * 256 + threadIdx.x;   // < 64*1280
  int n = i / LOC_;
  int q = i - n * LOC_;
  float s = 0.f;
#pragma unroll
  for (int sg = 0; sg < SEGC; ++sg) s += locP[(size_t)sg * (N_ * LOC_) + i];
  float sc = lg[q] / sqrtf(lv[q] + 1e-5f);
  float v = (s + lb[q] - lm[q]) * sc + lbe[q];
  catB[(size_t)n * CM_ + q] = f2bf(fmaxf(v, 0.f));
}

// merge GEMM partials: catB(bf16) x merge_w^T -> mrgP[seg][64][2048] (f32)
__global__ __launch_bounds__(256) void kD(const unsigned short* __restrict__ catB,
                                          const float* __restrict__ merge_w,
                                          float* __restrict__ mrgP) {
  __shared__ unsigned short As[64 * WPITCH];
  __shared__ unsigned short Ws[64 * WPITCH];
  int b  = blockIdx.x;            // 416 = 32 jt * 13 sg
  int jt = b / SEGM;
  int sg = b - jt * SEGM;
  const int t = threadIdx.x, row = t >> 2, kq = t & 3, w = t >> 6, l = t & 63;
  const uint4*  aRow = (const uint4*)catB + (size_t)row * 416 + sg * 32 + kq * 2;
  const float4* wRow = (const float4*)(merge_w + (size_t)(jt * 64 + row) * CM_
                                       + sg * 256 + kq * 16);
  f32x4 acc[4] = {{0,0,0,0},{0,0,0,0},{0,0,0,0},{0,0,0,0}};
  mfma_seg(aRow, wRow, As, Ws, acc);
  float* outp = mrgP + (size_t)sg * (N_ * C_);
#pragma unroll
  for (int jm = 0; jm < 4; ++jm)
#pragma unroll
    for (int r = 0; r < 4; ++r)
      outp[(size_t)(16 * w + (l >> 4) * 4 + r) * C_ + jt * 64 + jm * 16 + (l & 15)]
        = acc[jm][r];
}

// reduce mrgP over segs + BN + ReLU + L2 normalize -> d_out (f32)
__global__ __launch_bounds__(256) void kE(const float* __restrict__ mrgP,
    const float* __restrict__ mb, const float* __restrict__ mg, const float* __restrict__ mbe,
    const float* __restrict__ mm, const float* __restrict__ mv,
    float* __restrict__ out) {
  int n = blockIdx.x, t = threadIdx.x;
  float z[8]; float ss = 0.f;
#pragma unroll
  for (int r = 0; r < 8; ++r) {
    int j = t + (r << 8);
    float y = 0.f;
#pragma unroll
    for (int sg = 0; sg < SEGM; ++sg) y += mrgP[(size_t)sg * (N_ * C_) + (size_t)n * C_ + j];
    float sc = mg[j] / sqrtf(mv[j] + 1e-5f);
    float v = (y + mb[j] - mm[j]) * sc + mbe[j];
    v = fmaxf(v, 0.f);
    z[r] = v; ss += v * v;
  }
#pragma unroll
  for (int off = 32; off; off >>= 1) ss += __shfl_xor(ss, off, 64);
  __shared__ float red[4];
  if ((t & 63) == 0) red[t >> 6] = ss;
  __syncthreads();
  float tot = red[0] + red[1] + red[2] + red[3];
  float inv = 1.f / fmaxf(sqrtf(tot), 1e-12f);
#pragma unroll
  for (int r = 0; r < 8; ++r) out[(size_t)n * C_ + t + (r << 8)] = z[r] * inv;
}

extern "C" void kernel_launch(void* const* d_in, const int* in_sizes, int n_in,
                              void* d_out, int out_size, void* d_ws, size_t ws_size,
                              hipStream_t stream) {
  const float* x          = (const float*)d_in[0];
  const float* poses      = (const float*)d_in[1];
  const float* local_w    = (const float*)d_in[2];
  const float* local_b    = (const float*)d_in[3];
  const float* local_g    = (const float*)d_in[4];
  const float* local_be   = (const float*)d_in[5];
  const float* local_m    = (const float*)d_in[6];
  const float* local_v    = (const float*)d_in[7];
  const float* merge_w    = (const float*)d_in[8];
  const float* merge_b    = (const float*)d_in[9];
  const float* merge_g    = (const float*)d_in[10];
  const float* merge_be   = (const float*)d_in[11];
  const float* merge_m    = (const float*)d_in[12];
  const float* merge_v    = (const float*)d_in[13];

  char* ws = (char*)d_ws;
  unsigned short* catB = (unsigned short*)ws;                 // 64*3328 bf16  = 425984 B
  unsigned short* avgB = (unsigned short*)(ws + 425984);      // 64*5*2048 bf16 = 1310720 B
  float* locP = (float*)(ws + 1736704);                       // 8*64*1280 f32  = 2621440 B
  float* mrgP = (float*)(ws + 4358144);                       // 13*64*2048 f32 = 6815744 B

  kB<<<512, 256, 0, stream>>>(x, poses, avgB, catB);
  kC<<<20 * SEGC, 256, 0, stream>>>(avgB, local_w, locP);
  kC2<<<(N_ * LOC_) / 256, 256, 0, stream>>>(locP, local_b, local_g, local_be,
                                             local_m, local_v, catB);
  kD<<<32 * SEGM, 256, 0, stream>>>(catB, merge_w, mrgP);
  kE<<<N_, 256, 0, stream>>>(mrgP, merge_b, merge_g, merge_be, merge_m, merge_v,
                             (float*)d_out);
}